// Round 1
// 757.162 us; speedup vs baseline: 1.0285x; 1.0285x over previous
//
#include <hip/hip_runtime.h>
#include <hip/hip_bf16.h>
#include <cstdint>
#include <cstddef>

#define DIM 25
#define NN 20000
#define NE 320000
#define NF 300
#define NH 64
#define NC 50
#define K2 (DIM*NH)   // 1600
#define KP1 320       // layer-1 K padded (300 -> 320)
#define B1T_ROWS 1664 // chunks {8,8,8,1} branches -> {512,512,512,128} rows
#define B2T_ROWS 1280 // 25*50=1250 padded to 10*128
#define NBK 79        // row buckets of 256 rows
#define EPB 4096      // edges per binning block
#define BPB ((NE + EPB - 1) / EPB)  // 79
#define FCAP 5632     // fixed bucket slot capacity (mean 4096 + 24 sigma)

typedef __attribute__((ext_vector_type(8))) short short8;
typedef __attribute__((ext_vector_type(4))) float floatx4;
typedef __hip_bfloat16 bf16;

static __device__ __forceinline__ unsigned bf16bits(float f) {
    bf16 b = __float2bfloat16(f);
    return (unsigned)*reinterpret_cast<unsigned short*>(&b);
}
static __device__ __forceinline__ float blo(unsigned w) { return __uint_as_float(w << 16); }
static __device__ __forceinline__ float bhi(unsigned w) { return __uint_as_float(w & 0xFFFF0000u); }

// async global->LDS, 16B per lane; LDS dest = wave-uniform base + lane*16
static __device__ __forceinline__ void gld16(const void* g, void* l) {
    __builtin_amdgcn_global_load_lds((const __attribute__((address_space(1))) unsigned*)g,
                                     (__attribute__((address_space(3))) unsigned*)l, 16, 0, 0);
}

// ---------------- utility ----------------
__global__ void zero_kernel(int* __restrict__ p, int n) {
    int i = blockIdx.x * blockDim.x + threadIdx.x;
    if (i < n) p[i] = 0;
}

// ---------------- CSR build ----------------
__global__ __launch_bounds__(256) void bucket_scatter_kernel(const int* __restrict__ rows,
                                                             const int* __restrict__ cols,
                                                             const float* __restrict__ vals,
                                                             int* __restrict__ gcur,
                                                             unsigned* __restrict__ interE,
                                                             unsigned char* __restrict__ interR) {
    const int d = blockIdx.y;
    const int e0 = blockIdx.x * EPB;
    __shared__ int lh[NBK];
    __shared__ int lo[NBK];
    __shared__ int lbase[NBK];
    __shared__ unsigned entE[EPB];        // 16 KB
    __shared__ unsigned short entR[EPB];  // 8 KB
    const int tid = threadIdx.x;
    for (int i = tid; i < NBK; i += 256) lh[i] = 0;
    __syncthreads();
    const int* rd = rows + (size_t)d * NE;
    const int* cd = cols + (size_t)d * NE;
    const float* vd = vals + (size_t)d * NE;
    const int e1 = min(e0 + EPB, NE);
    const int ne = e1 - e0;
    for (int i = e0 + tid; i < e1; i += 256)
        atomicAdd(&lh[rd[i] >> 8], 1);
    __syncthreads();
    if (tid == 0) {
        int run = 0;
        for (int b = 0; b < NBK; ++b) { lo[b] = run; run += lh[b]; }
    }
    __syncthreads();
    for (int i = tid; i < NBK; i += 256) {
        lbase[i] = lh[i] ? atomicAdd(&gcur[d * NBK + i], lh[i]) : 0;
        lh[i] = 0;
    }
    __syncthreads();
    for (int i = e0 + tid; i < e1; i += 256) {
        int r = rd[i];
        int b = r >> 8;
        int rank = atomicAdd(&lh[b], 1);
        int pos = lo[b] + rank;
        entE[pos] = (unsigned)cd[i] | (bf16bits(vd[i]) << 16);
        entR[pos] = (unsigned short)r;
    }
    __syncthreads();
    for (int p = tid; p < ne; p += 256) {
        int r = entR[p];
        int b = r >> 8;
        int gpos = lbase[b] + (p - lo[b]);
        if (gpos < FCAP) {
            size_t slot = ((size_t)d * NBK + b) * FCAP + gpos;
            interE[slot] = entE[p];
            interR[slot] = (unsigned char)r;
        }
    }
}

__global__ void bucket_scan_kernel(const int* __restrict__ gcur,
                                   int* __restrict__ offs_b,
                                   int* __restrict__ bcnt,
                                   int* __restrict__ offs) {
    const int d = blockIdx.x;
    if (threadIdx.x != 0) return;
    int run = 0;
    for (int b = 0; b < NBK; ++b) {
        int c = min(gcur[d * NBK + b], FCAP);
        offs_b[d * NBK + b] = run;
        bcnt[d * NBK + b] = c;
        run += c;
    }
    offs[d * (NN + 1) + NN] = run;
}

__global__ __launch_bounds__(256) void csr_finalize_kernel(const unsigned* __restrict__ interE,
                                                           const unsigned char* __restrict__ interR,
                                                           const int* __restrict__ offs_b,
                                                           const int* __restrict__ bcnt,
                                                           int* __restrict__ offs,
                                                           unsigned* __restrict__ sedge) {
    const int d = blockIdx.y;
    const int b = blockIdx.x;
    const int tid = threadIdx.x;
    const int s = offs_b[d * NBK + b];
    const int cnt = bcnt[d * NBK + b];
    const size_t base = ((size_t)d * NBK + b) * FCAP;
    __shared__ int sm[256];
    __shared__ int cur[256];
    __shared__ unsigned lse[FCAP];  // 22 KB
    sm[tid] = 0;
    __syncthreads();
    for (int i = tid; i < cnt; i += 256)
        atomicAdd(&sm[interR[base + i]], 1);
    __syncthreads();
    int own = sm[tid];
    for (int off = 1; off < 256; off <<= 1) {
        int t = (tid >= off) ? sm[tid - off] : 0;
        __syncthreads();
        sm[tid] += t;
        __syncthreads();
    }
    int excl = sm[tid] - own;
    int row = (b << 8) + tid;
    if (row < NN) offs[d * (NN + 1) + row] = s + excl;
    cur[tid] = excl;
    __syncthreads();
    for (int i = tid; i < cnt; i += 256) {
        int idx = atomicAdd(&cur[interR[base + i]], 1);
        lse[idx] = interE[base + i];
    }
    __syncthreads();
    unsigned* sed = sedge + (size_t)d * NE;
    for (int t = tid; t < cnt; t += 256)
        sed[s + t] = lse[t];
}

// ---------------- packing ----------------
__global__ void pack_x_kernel(const float* __restrict__ x, bf16* __restrict__ xb) {
    int i = blockIdx.x * blockDim.x + threadIdx.x;
    if (i >= NN * KP1) return;
    int n = i / KP1, k = i - n * KP1;
    xb[i] = __float2bfloat16((k < NF) ? x[(size_t)n * NF + k] : 0.f);
}

// chunks {8,8,8,1}: chunk c rows [c*512, ...), row r -> branch c*8 + (r>>6), h = r&63
__global__ void pack_b1_kernel(const float* __restrict__ W1, bf16* __restrict__ b1t) {
    int i = blockIdx.x * blockDim.x + threadIdx.x;
    if (i >= B1T_ROWS * KP1) return;
    int j2 = i / KP1, k = i - j2 * KP1;
    int chunk = j2 >> 9;
    int r = j2 & 511;
    int d = chunk * 8 + (r >> 6);
    float v = 0.f;
    if (d < DIM && k < NF)
        v = W1[(size_t)d * NF * NH + (size_t)k * NH + (r & 63)];
    b1t[i] = __float2bfloat16(v);
}

__global__ void pack_b2_kernel(const float* __restrict__ W2, bf16* __restrict__ b2t) {
    int i = blockIdx.x * blockDim.x + threadIdx.x;
    if (i >= B2T_ROWS * K2) return;
    int r = i / K2, k = i - r * K2;
    float v = 0.f;
    if (r < DIM * NC) {
        int g = r / NC, c = r - g * NC;
        v = W2[(size_t)g * K2 * NC + (size_t)k * NC + c];
    }
    b2t[i] = __float2bfloat16(v);
}

// ---------------- bf16 MFMA GEMM, double-buffered prefetch + grouped raster + LDS swizzle ----
// mode 1: n -> (g=n>>6, h=n&63), C[g][m][64];  mode 2: n -> (g=n/50, c=n%50), C[g][m][50]
// LDS tile [128][32] entries (64B row stride). Bank fix: 16B chunk c of row r stored at
// LDS chunk c ^ ((r>>1)&3) -- applied on the GLOBAL source address (gld_lds dest must stay
// linear) and mirrored on the ds_read address. Read aliasing drops 8-way -> 2-way (free).
__global__ __launch_bounds__(256) void gemm_bf16_kernel(const bf16* __restrict__ A, int lda,
                                                        const bf16* __restrict__ BT, int ldb,
                                                        bf16* __restrict__ C,
                                                        int ksteps, int mode, int nvalid) {
    __shared__ unsigned short As[2 * 128 * 32];   // 16 KB x2 buffers
    __shared__ unsigned short Bs[2 * 128 * 32];
    const int tid = threadIdx.x;
    const int wave = tid >> 6;
    const int lane = tid & 63;

    // grouped rasterization: n-tile fastest within groups of 8 m-tiles.
    // keeps the live A working set ~3 MB so staged loads hit L2/L3, A fetched ~once.
    const int mtiles = (int)gridDim.x;
    const int ntiles = (int)gridDim.y;
    const int bid = (int)blockIdx.y * mtiles + (int)blockIdx.x;
    const int per_group = 8 * ntiles;
    const int group = bid / per_group;
    const int rem = bid - group * per_group;
    const int first_m = group * 8;
    const int gm = min(8, mtiles - first_m);
    const int mt = first_m + rem % gm;
    const int nt = rem / gm;
    const int m0 = mt * 128;
    const int n0 = nt * 128;

    const int wm = (wave >> 1) * 64;
    const int wn = (wave & 1) * 64;
    floatx4 acc[4][4] = {};
    const int r0 = tid >> 2;                       // staging row 0..63
    const int cg = (tid & 3) ^ ((r0 >> 1) & 3);    // swizzled global source chunk
    const int q8 = (lane >> 4) * 8;
    const int gq = q8 >> 3;                        // global chunk wanted by frag read
    // wave-uniform LDS staging bases (per buffer), lane*16B added by HW
    unsigned short* lA0 = As + wave * 512;
    unsigned short* lA1 = As + 2048 + wave * 512;
    unsigned short* lB0 = Bs + wave * 512;
    unsigned short* lB1 = Bs + 2048 + wave * 512;
    const bf16* gA0 = A + (size_t)(m0 + r0) * lda + cg * 8;
    const bf16* gA1 = A + (size_t)(m0 + r0 + 64) * lda + cg * 8;
    const bf16* gB0 = BT + (size_t)(n0 + r0) * ldb + cg * 8;
    const bf16* gB1 = BT + (size_t)(n0 + r0 + 64) * ldb + cg * 8;

    // loop-invariant swizzled read offsets (entries)
    int offA[4], offB[4];
    #pragma unroll
    for (int i = 0; i < 4; ++i) {
        int ra = wm + i * 16 + (lane & 15);
        int rb = wn + i * 16 + (lane & 15);
        offA[i] = ra * 32 + ((gq ^ ((ra >> 1) & 3)) << 3);
        offB[i] = rb * 32 + ((gq ^ ((rb >> 1) & 3)) << 3);
    }

    // prologue: stage K-step 0 into buffer 0
    gld16(gA0, lA0); gld16(gA1, lA1); gld16(gB0, lB0); gld16(gB1, lB1);
    __syncthreads();   // vmcnt(0) drained before barrier -> buffer 0 visible

    int cur = 0;
    for (int ks = 0; ks < ksteps; ++ks) {
        // issue next K-step's loads into the other buffer; they stay in flight
        // under this step's ds_read+MFMA and are drained by the end-of-iter barrier.
        if (ks + 1 < ksteps) {
            const int nb = cur ^ 1;
            const size_t ko = (size_t)(ks + 1) * 32;
            gld16(gA0 + ko, lA0 + nb * 4096); gld16(gA1 + ko, lA1 + nb * 4096);
            gld16(gB0 + ko, lB0 + nb * 4096); gld16(gB1 + ko, lB1 + nb * 4096);
        }
        const unsigned short* as = As + cur * 4096;
        const unsigned short* bs = Bs + cur * 4096;
        short8 af[4], bfr[4];
        #pragma unroll
        for (int i = 0; i < 4; ++i) {
            af[i]  = *(const short8*)&as[offA[i]];
            bfr[i] = *(const short8*)&bs[offB[i]];
        }
        #pragma unroll
        for (int i = 0; i < 4; ++i)
            #pragma unroll
            for (int j = 0; j < 4; ++j)
                acc[i][j] = __builtin_amdgcn_mfma_f32_16x16x32_bf16(af[i], bfr[j], acc[i][j], 0, 0, 0);
        __syncthreads();   // drains vmcnt(0): next buffer staged; lgkm: reads of cur done
        cur ^= 1;
    }
    const int cr = (lane >> 4) * 4;
    const int cc = lane & 15;
    #pragma unroll
    for (int i = 0; i < 4; ++i) {
        #pragma unroll
        for (int r = 0; r < 4; ++r) {
            int m = m0 + wm + i * 16 + cr + r;
            if (m >= NN) continue;
            #pragma unroll
            for (int j = 0; j < 4; ++j) {
                int n = n0 + wn + j * 16 + cc;
                if (n >= nvalid) continue;
                if (mode == 1) {
                    int g = n >> 6, h = n & 63;
                    C[(size_t)g * NN * NH + (size_t)m * NH + h] = __float2bfloat16(acc[i][j][r]);
                } else {
                    int g = n / NC, c = n - g * NC;
                    C[(size_t)g * NN * NC + (size_t)m * NC + c] = __float2bfloat16(acc[i][j][r]);
                }
            }
        }
    }
}

// ---------------- SPMM1: branch-pinned blocks (g = bid % CHk -> XCD), 2 nodes/wave ----------------
__global__ __launch_bounds__(256) void spmm1_kernel(const bf16* __restrict__ sup,
                                                    const int* __restrict__ offs,
                                                    const unsigned* __restrict__ sedge,
                                                    const float* __restrict__ b1,
                                                    bf16* __restrict__ h1cat, int d0, int CHk) {
    const int i = blockIdx.x;
    const int g = i % CHk;
    const int nb = i / CHk;
    const int tid = threadIdx.x;
    const int lane = tid & 63;
    const int n = nb * 8 + ((tid >> 6) << 1) + (lane >> 5);
    const int hl = lane & 31;
    const int d = d0 + g;
    const int s = offs[d * (NN + 1) + n];
    const int e = offs[d * (NN + 1) + n + 1];
    const char* supd = (const char*)sup + (size_t)g * NN * NH * 2;
    const unsigned* sed = sedge + (size_t)d * NE;
    const unsigned hoff = (unsigned)hl * 4;
    float alo0 = 0.f, ahi0 = 0.f, alo1 = 0.f, ahi1 = 0.f;
    int j = s;
    for (; j + 4 <= e; j += 4) {
        unsigned e0 = sed[j], e1 = sed[j + 1], e2 = sed[j + 2], e3 = sed[j + 3];
        unsigned w0 = *(const unsigned*)(supd + (((e0 & 0xFFFFu) << 7) | hoff));
        unsigned w1 = *(const unsigned*)(supd + (((e1 & 0xFFFFu) << 7) | hoff));
        unsigned w2 = *(const unsigned*)(supd + (((e2 & 0xFFFFu) << 7) | hoff));
        unsigned w3 = *(const unsigned*)(supd + (((e3 & 0xFFFFu) << 7) | hoff));
        float v0 = bhi(e0), v1 = bhi(e1), v2 = bhi(e2), v3 = bhi(e3);
        alo0 = fmaf(v0, blo(w0), alo0); ahi0 = fmaf(v0, bhi(w0), ahi0);
        alo1 = fmaf(v1, blo(w1), alo1); ahi1 = fmaf(v1, bhi(w1), ahi1);
        alo0 = fmaf(v2, blo(w2), alo0); ahi0 = fmaf(v2, bhi(w2), ahi0);
        alo1 = fmaf(v3, blo(w3), alo1); ahi1 = fmaf(v3, bhi(w3), ahi1);
    }
    for (; j < e; ++j) {
        unsigned e0 = sed[j];
        unsigned w0 = *(const unsigned*)(supd + (((e0 & 0xFFFFu) << 7) | hoff));
        float v0 = bhi(e0);
        alo0 = fmaf(v0, blo(w0), alo0); ahi0 = fmaf(v0, bhi(w0), ahi0);
    }
    float alo = fmaxf((alo0 + alo1) + b1[d * NH + 2 * hl], 0.f);
    float ahi = fmaxf((ahi0 + ahi1) + b1[d * NH + 2 * hl + 1], 0.f);
    unsigned packed = bf16bits(alo) | (bf16bits(ahi) << 16);
    *(unsigned*)((char*)h1cat + ((size_t)n * K2 + d * NH) * 2 + hoff) = packed;
}

// ---------------- SPMM2 stage 1: branch d pinned to XCD d%8 (d=24 spread), relu'd bf16x2 ----------------
__global__ __launch_bounds__(256) void spmm2b_kernel(const bf16* __restrict__ sup2,
                                                     const int* __restrict__ offs,
                                                     const unsigned* __restrict__ sedge,
                                                     const float* __restrict__ b2,
                                                     unsigned* __restrict__ h2u) {
    const int i = blockIdx.x;
    const int r = i & 7;
    const int q = i >> 3;           // [0, 7813)
    int d, nb;
    if (q < 7500) { d = r + 8 * (q / 2500); nb = q % 2500; }
    else { d = 24; nb = (q - 7500) * 8 + r; if (nb >= 2500) return; }
    const int tid = threadIdx.x;
    const int lane = tid & 63;
    const int n = nb * 8 + ((tid >> 6) << 1) + (lane >> 5);
    const int cl = min(lane & 31, 24);      // class pair 2cl,2cl+1; lanes 25-31 dup
    const unsigned coff = (unsigned)cl * 4;
    const int s = offs[d * (NN + 1) + n];
    const int e = offs[d * (NN + 1) + n + 1];
    const char* supd = (const char*)sup2 + (size_t)d * NN * NC * 2;
    const unsigned* sed = sedge + (size_t)d * NE;
    float alo0 = b2[d * NC + 2 * cl], ahi0 = b2[d * NC + 2 * cl + 1];
    float alo1 = 0.f, ahi1 = 0.f;
    int j = s;
    for (; j + 4 <= e; j += 4) {
        unsigned e0 = sed[j], e1 = sed[j + 1], e2 = sed[j + 2], e3 = sed[j + 3];
        unsigned w0 = *(const unsigned*)(supd + ((e0 & 0xFFFFu) * 100u + coff));
        unsigned w1 = *(const unsigned*)(supd + ((e1 & 0xFFFFu) * 100u + coff));
        unsigned w2 = *(const unsigned*)(supd + ((e2 & 0xFFFFu) * 100u + coff));
        unsigned w3 = *(const unsigned*)(supd + ((e3 & 0xFFFFu) * 100u + coff));
        float v0 = bhi(e0), v1 = bhi(e1), v2 = bhi(e2), v3 = bhi(e3);
        alo0 = fmaf(v0, blo(w0), alo0); ahi0 = fmaf(v0, bhi(w0), ahi0);
        alo1 = fmaf(v1, blo(w1), alo1); ahi1 = fmaf(v1, bhi(w1), ahi1);
        alo0 = fmaf(v2, blo(w2), alo0); ahi0 = fmaf(v2, bhi(w2), ahi0);
        alo1 = fmaf(v3, blo(w3), alo1); ahi1 = fmaf(v3, bhi(w3), ahi1);
    }
    for (; j < e; ++j) {
        unsigned e0 = sed[j];
        unsigned w0 = *(const unsigned*)(supd + ((e0 & 0xFFFFu) * 100u + coff));
        float v0 = bhi(e0);
        alo0 = fmaf(v0, blo(w0), alo0); ahi0 = fmaf(v0, bhi(w0), ahi0);
    }
    float alo = fmaxf(alo0 + alo1, 0.f);
    float ahi = fmaxf(ahi0 + ahi1, 0.f);
    if ((lane & 31) < 25)
        h2u[((size_t)d * NN + n) * 25 + cl] = bf16bits(alo) | (bf16bits(ahi) << 16);
}

// ---------------- SPMM2 stage 2: streaming max over branches ----------------
__global__ __launch_bounds__(256) void maxk_kernel(const unsigned* __restrict__ h2u,
                                                   float* __restrict__ out) {
    int i = blockIdx.x * blockDim.x + threadIdx.x;   // [0, NN*25)
    if (i >= NN * 25) return;
    int n = i / 25, cl = i - n * 25;
    float mlo = 0.f, mhi = 0.f;
    #pragma unroll
    for (int d = 0; d < DIM; ++d) {
        unsigned w = h2u[(size_t)d * NN * 25 + i];
        mlo = fmaxf(mlo, blo(w));
        mhi = fmaxf(mhi, bhi(w));
    }
    *(float2*)&out[(size_t)n * NC + 2 * cl] = make_float2(mlo, mhi);
}

extern "C" void kernel_launch(void* const* d_in, const int* in_sizes, int n_in,
                              void* d_out, int out_size, void* d_ws, size_t ws_size,
                              hipStream_t stream) {
    const float* x    = (const float*)d_in[0];
    const int*   rows = (const int*)d_in[1];
    const int*   cols = (const int*)d_in[2];
    const float* vals = (const float*)d_in[3];
    const float* W1   = (const float*)d_in[4];
    const float* b1   = (const float*)d_in[5];
    const float* W2   = (const float*)d_in[6];
    const float* b2   = (const float*)d_in[7];
    float* out = (float*)d_out;

    char* ws = (char*)d_ws;
    size_t off = 0;
    auto alloc = [&](size_t bytes) {
        void* p = ws + off;
        off += (bytes + 255) & ~(size_t)255;
        return p;
    };
    bf16* supbuf = (bf16*)alloc(sizeof(bf16) * (size_t)DIM * NN * NC);   // 50 MB
    bf16* h1cat  = (bf16*)alloc(sizeof(bf16) * (size_t)NN * K2);         // 64 MB (aliases inter & h2)
    bf16* b1t    = (bf16*)alloc(sizeof(bf16) * (size_t)B1T_ROWS * KP1);  // 1.07 MB
    bf16* b2t    = (bf16*)alloc(sizeof(bf16) * (size_t)B2T_ROWS * K2);   // 4.1 MB
    int*  offs   = (int*)alloc(sizeof(int) * (size_t)DIM * (NN + 1));    // 2 MB
    int*  gcur   = (int*)alloc(sizeof(int) * (size_t)DIM * NBK);
    int*  offs_b = (int*)alloc(sizeof(int) * (size_t)DIM * NBK);
    int*  bcnt   = (int*)alloc(sizeof(int) * (size_t)DIM * NBK);
    unsigned* sedge = (unsigned*)alloc(sizeof(unsigned) * (size_t)DIM * NE); // 32 MB

    bf16* sup1 = supbuf;                                   // [<=8][NN][64] = 20.5 MB
    bf16* xbf  = supbuf + (size_t)12 * 1024 * 1024;        // +24 MB (12.8 MB)
    bf16* sup2 = supbuf;                                   // [25][NN][50]
    unsigned* interE = (unsigned*)h1cat;
    unsigned char* interR = (unsigned char*)h1cat + (size_t)DIM * NBK * FCAP * 4;
    unsigned* h2u = (unsigned*)h1cat;                      // 50 MB, h1cat dead after gemm2

    if (off > ws_size) return;  // diagnostic guard (~153 MB, known-safe)

    // CSR build
    zero_kernel<<<(DIM * NBK + 255) / 256, 256, 0, stream>>>(gcur, DIM * NBK);
    bucket_scatter_kernel<<<dim3(BPB, DIM), 256, 0, stream>>>(rows, cols, vals, gcur, interE, interR);
    bucket_scan_kernel<<<DIM, 64, 0, stream>>>(gcur, offs_b, bcnt, offs);
    csr_finalize_kernel<<<dim3(NBK, DIM), 256, 0, stream>>>(interE, interR, offs_b, bcnt, offs, sedge);

    // Packing
    pack_x_kernel<<<(NN * KP1 + 255) / 256, 256, 0, stream>>>(x, xbf);
    pack_b1_kernel<<<(B1T_ROWS * KP1 + 255) / 256, 256, 0, stream>>>(W1, b1t);
    pack_b2_kernel<<<(B2T_ROWS * K2 + 255) / 256, 256, 0, stream>>>(W2, b2t);

    const int mtiles = (NN + 127) / 128;  // 157

    // Layer 1: chunks of {8,8,8,1} branches (branch -> XCD pinning in spmm1)
    const int cstart[4] = {0, 8, 16, 24};
    const int csize[4]  = {8, 8, 8, 1};
    const int crow[4]   = {0, 512, 1024, 1536};
    for (int c = 0; c < 4; ++c) {
        int nv = csize[c] * 64;
        gemm_bf16_kernel<<<dim3(mtiles, (nv + 127) / 128), 256, 0, stream>>>(
            xbf, KP1, b1t + (size_t)crow[c] * KP1, KP1, sup1, KP1 / 32, 1, nv);
        spmm1_kernel<<<csize[c] * (NN / 8), 256, 0, stream>>>(
            sup1, offs, sedge, b1, h1cat, cstart[c], csize[c]);
    }
    // Layer 2: GEMM [20000x1600]@[1600x1280] -> sup2; branch-pinned spmm2 -> h2; max -> out
    gemm_bf16_kernel<<<dim3(mtiles, B2T_ROWS / 128), 256, 0, stream>>>(
        h1cat, K2, b2t, K2, sup2, K2 / 32, 2, DIM * NC);
    spmm2b_kernel<<<8 * 7813, 256, 0, stream>>>(sup2, offs, sedge, b2, h2u);
    maxk_kernel<<<(NN * 25 + 255) / 256, 256, 0, stream>>>(h2u, out);
}

// Round 2
// 755.515 us; speedup vs baseline: 1.0308x; 1.0022x over previous
//
#include <hip/hip_runtime.h>
#include <hip/hip_bf16.h>
#include <cstdint>
#include <cstddef>

#define DIM 25
#define NN 20000
#define NE 320000
#define NF 300
#define NH 64
#define NC 50
#define K2 (DIM*NH)   // 1600
#define KP1 320       // layer-1 K padded (300 -> 320)
#define B1T_ROWS 1664 // chunks {8,8,8,1} branches -> {512,512,512,128} rows
#define B2T_ROWS 1280 // 25*50=1250 padded to 10*128
#define NBK 79        // row buckets of 256 rows
#define EPB 4096      // edges per binning block
#define BPB ((NE + EPB - 1) / EPB)  // 79
#define FCAP 5632     // fixed bucket slot capacity (mean 4096 + 24 sigma)

typedef __attribute__((ext_vector_type(8))) short short8;
typedef __attribute__((ext_vector_type(4))) float floatx4;
typedef __hip_bfloat16 bf16;

static __device__ __forceinline__ unsigned bf16bits(float f) {
    bf16 b = __float2bfloat16(f);
    return (unsigned)*reinterpret_cast<unsigned short*>(&b);
}
static __device__ __forceinline__ float blo(unsigned w) { return __uint_as_float(w << 16); }
static __device__ __forceinline__ float bhi(unsigned w) { return __uint_as_float(w & 0xFFFF0000u); }

// async global->LDS, 16B per lane; LDS dest = wave-uniform base + lane*16
static __device__ __forceinline__ void gld16(const void* g, void* l) {
    __builtin_amdgcn_global_load_lds((const __attribute__((address_space(1))) unsigned*)g,
                                     (__attribute__((address_space(3))) unsigned*)l, 16, 0, 0);
}

// ---------------- utility ----------------
__global__ void zero_kernel(int* __restrict__ p, int n) {
    int i = blockIdx.x * blockDim.x + threadIdx.x;
    if (i < n) p[i] = 0;
}

// ---------------- CSR build ----------------
__global__ __launch_bounds__(256) void bucket_scatter_kernel(const int* __restrict__ rows,
                                                             const int* __restrict__ cols,
                                                             const float* __restrict__ vals,
                                                             int* __restrict__ gcur,
                                                             unsigned* __restrict__ interE,
                                                             unsigned char* __restrict__ interR) {
    const int d = blockIdx.y;
    const int e0 = blockIdx.x * EPB;
    __shared__ int lh[NBK];
    __shared__ int lo[NBK];
    __shared__ int lbase[NBK];
    __shared__ unsigned entE[EPB];        // 16 KB
    __shared__ unsigned short entR[EPB];  // 8 KB
    const int tid = threadIdx.x;
    for (int i = tid; i < NBK; i += 256) lh[i] = 0;
    __syncthreads();
    const int* rd = rows + (size_t)d * NE;
    const int* cd = cols + (size_t)d * NE;
    const float* vd = vals + (size_t)d * NE;
    const int e1 = min(e0 + EPB, NE);
    const int ne = e1 - e0;
    for (int i = e0 + tid; i < e1; i += 256)
        atomicAdd(&lh[rd[i] >> 8], 1);
    __syncthreads();
    if (tid == 0) {
        int run = 0;
        for (int b = 0; b < NBK; ++b) { lo[b] = run; run += lh[b]; }
    }
    __syncthreads();
    for (int i = tid; i < NBK; i += 256) {
        lbase[i] = lh[i] ? atomicAdd(&gcur[d * NBK + i], lh[i]) : 0;
        lh[i] = 0;
    }
    __syncthreads();
    for (int i = e0 + tid; i < e1; i += 256) {
        int r = rd[i];
        int b = r >> 8;
        int rank = atomicAdd(&lh[b], 1);
        int pos = lo[b] + rank;
        entE[pos] = (unsigned)cd[i] | (bf16bits(vd[i]) << 16);
        entR[pos] = (unsigned short)r;
    }
    __syncthreads();
    for (int p = tid; p < ne; p += 256) {
        int r = entR[p];
        int b = r >> 8;
        int gpos = lbase[b] + (p - lo[b]);
        if (gpos < FCAP) {
            size_t slot = ((size_t)d * NBK + b) * FCAP + gpos;
            interE[slot] = entE[p];
            interR[slot] = (unsigned char)r;
        }
    }
}

__global__ void bucket_scan_kernel(const int* __restrict__ gcur,
                                   int* __restrict__ offs_b,
                                   int* __restrict__ bcnt,
                                   int* __restrict__ offs) {
    const int d = blockIdx.x;
    if (threadIdx.x != 0) return;
    int run = 0;
    for (int b = 0; b < NBK; ++b) {
        int c = min(gcur[d * NBK + b], FCAP);
        offs_b[d * NBK + b] = run;
        bcnt[d * NBK + b] = c;
        run += c;
    }
    offs[d * (NN + 1) + NN] = run;
}

__global__ __launch_bounds__(256) void csr_finalize_kernel(const unsigned* __restrict__ interE,
                                                           const unsigned char* __restrict__ interR,
                                                           const int* __restrict__ offs_b,
                                                           const int* __restrict__ bcnt,
                                                           int* __restrict__ offs,
                                                           unsigned* __restrict__ sedge) {
    const int d = blockIdx.y;
    const int b = blockIdx.x;
    const int tid = threadIdx.x;
    const int s = offs_b[d * NBK + b];
    const int cnt = bcnt[d * NBK + b];
    const size_t base = ((size_t)d * NBK + b) * FCAP;
    __shared__ int sm[256];
    __shared__ int cur[256];
    __shared__ unsigned lse[FCAP];  // 22 KB
    sm[tid] = 0;
    __syncthreads();
    for (int i = tid; i < cnt; i += 256)
        atomicAdd(&sm[interR[base + i]], 1);
    __syncthreads();
    int own = sm[tid];
    for (int off = 1; off < 256; off <<= 1) {
        int t = (tid >= off) ? sm[tid - off] : 0;
        __syncthreads();
        sm[tid] += t;
        __syncthreads();
    }
    int excl = sm[tid] - own;
    int row = (b << 8) + tid;
    if (row < NN) offs[d * (NN + 1) + row] = s + excl;
    cur[tid] = excl;
    __syncthreads();
    for (int i = tid; i < cnt; i += 256) {
        int idx = atomicAdd(&cur[interR[base + i]], 1);
        lse[idx] = interE[base + i];
    }
    __syncthreads();
    unsigned* sed = sedge + (size_t)d * NE;
    for (int t = tid; t < cnt; t += 256)
        sed[s + t] = lse[t];
}

// ---------------- packing ----------------
__global__ void pack_x_kernel(const float* __restrict__ x, bf16* __restrict__ xb) {
    int i = blockIdx.x * blockDim.x + threadIdx.x;
    if (i >= NN * KP1) return;
    int n = i / KP1, k = i - n * KP1;
    xb[i] = __float2bfloat16((k < NF) ? x[(size_t)n * NF + k] : 0.f);
}

// chunks {8,8,8,1}: chunk c rows [c*512, ...), row r -> branch c*8 + (r>>6), h = r&63
__global__ void pack_b1_kernel(const float* __restrict__ W1, bf16* __restrict__ b1t) {
    int i = blockIdx.x * blockDim.x + threadIdx.x;
    if (i >= B1T_ROWS * KP1) return;
    int j2 = i / KP1, k = i - j2 * KP1;
    int chunk = j2 >> 9;
    int r = j2 & 511;
    int d = chunk * 8 + (r >> 6);
    float v = 0.f;
    if (d < DIM && k < NF)
        v = W1[(size_t)d * NF * NH + (size_t)k * NH + (r & 63)];
    b1t[i] = __float2bfloat16(v);
}

__global__ void pack_b2_kernel(const float* __restrict__ W2, bf16* __restrict__ b2t) {
    int i = blockIdx.x * blockDim.x + threadIdx.x;
    if (i >= B2T_ROWS * K2) return;
    int r = i / K2, k = i - r * K2;
    float v = 0.f;
    if (r < DIM * NC) {
        int g = r / NC, c = r - g * NC;
        v = W2[(size_t)g * K2 * NC + (size_t)k * NC + c];
    }
    b2t[i] = __float2bfloat16(v);
}

// ---------------- bf16 MFMA GEMM: 3-buffer depth-2 pipeline, counted vmcnt, raw barrier ----
// mode 1: n -> (g=n>>6, h=n&63), C[g][m][64];  mode 2: n -> (g=n/50, c=n%50), C[g][m][50]
// LDS tile [128][32] entries (64B row stride), XOR-swizzled on global source + ds_read addr.
// Pipeline (NB=3): iter k waits vmcnt(4) (K-step k loads done, k+1 stays in flight),
// s_barrier, THEN issues K-step k+2 into buf (k+2)%3 -- that buffer was last read in
// interval k-1, whose ds_reads completed before barrier_k (MFMA consumption forces lgkm
// waits), so issue-after-barrier is race-free. No vmcnt(0) drain until the final step.
__global__ __launch_bounds__(256) void gemm_bf16_kernel(const bf16* __restrict__ A, int lda,
                                                        const bf16* __restrict__ BT, int ldb,
                                                        bf16* __restrict__ C,
                                                        int ksteps, int mode, int nvalid) {
    __shared__ unsigned short As[3 * 128 * 32];   // 24 KB
    __shared__ unsigned short Bs[3 * 128 * 32];   // 24 KB
    const int tid = threadIdx.x;
    const int wave = tid >> 6;
    const int lane = tid & 63;

    // grouped rasterization: n-tile fastest within groups of 8 m-tiles (A L2/L3 resident).
    const int mtiles = (int)gridDim.x;
    const int ntiles = (int)gridDim.y;
    const int bid = (int)blockIdx.y * mtiles + (int)blockIdx.x;
    const int per_group = 8 * ntiles;
    const int group = bid / per_group;
    const int rem = bid - group * per_group;
    const int first_m = group * 8;
    const int gm = min(8, mtiles - first_m);
    const int mt = first_m + rem % gm;
    const int nt = rem / gm;
    const int m0 = mt * 128;
    const int n0 = nt * 128;

    const int wm = (wave >> 1) * 64;
    const int wn = (wave & 1) * 64;
    floatx4 acc[4][4] = {};
    const int r0 = tid >> 2;                       // staging row 0..63
    const int cg = (tid & 3) ^ ((r0 >> 1) & 3);    // swizzled global source chunk
    const int q8 = (lane >> 4) * 8;
    const int gq = q8 >> 3;                        // global chunk wanted by frag read
    // wave-uniform LDS staging bases (buffer 0), lane*16B added by HW
    unsigned short* lA0 = As + wave * 512;
    unsigned short* lA1 = As + 2048 + wave * 512;
    unsigned short* lB0 = Bs + wave * 512;
    unsigned short* lB1 = Bs + 2048 + wave * 512;
    const bf16* gA0 = A + (size_t)(m0 + r0) * lda + cg * 8;
    const bf16* gA1 = A + (size_t)(m0 + r0 + 64) * lda + cg * 8;
    const bf16* gB0 = BT + (size_t)(n0 + r0) * ldb + cg * 8;
    const bf16* gB1 = BT + (size_t)(n0 + r0 + 64) * ldb + cg * 8;

    // loop-invariant swizzled read offsets (entries, relative to buffer base)
    int offA[4], offB[4];
    #pragma unroll
    for (int i = 0; i < 4; ++i) {
        int ra = wm + i * 16 + (lane & 15);
        int rb = wn + i * 16 + (lane & 15);
        offA[i] = ra * 32 + ((gq ^ ((ra >> 1) & 3)) << 3);
        offB[i] = rb * 32 + ((gq ^ ((rb >> 1) & 3)) << 3);
    }

    // prologue: stage K-step 0 -> buf0, K-step 1 -> buf1 (8 loads in flight)
    gld16(gA0, lA0); gld16(gA1, lA1); gld16(gB0, lB0); gld16(gB1, lB1);
    if (ksteps > 1) {
        gld16(gA0 + 32, lA0 + 4096); gld16(gA1 + 32, lA1 + 4096);
        gld16(gB0 + 32, lB0 + 4096); gld16(gB1 + 32, lB1 + 4096);
    }
    const bf16* pA0 = gA0 + 64;   // next-issue (K-step k+2) source pointers
    const bf16* pA1 = gA1 + 64;
    const bf16* pB0 = gB0 + 64;
    const bf16* pB1 = gB1 + 64;

    int buf = 0;    // buffer holding K-step k
    int pbuf = 2;   // buffer for K-step k+2
    for (int ks = 0; ks < ksteps; ++ks) {
        // wait only for K-step k's 4 loads (outstanding: k and k+1 = 8 -> vmcnt(4))
        if (ks + 1 < ksteps) asm volatile("s_waitcnt vmcnt(4)" ::: "memory");
        else                 asm volatile("s_waitcnt vmcnt(0)" ::: "memory");
        __builtin_amdgcn_sched_barrier(0);
        __builtin_amdgcn_s_barrier();
        __builtin_amdgcn_sched_barrier(0);
        // issue K-step k+2 loads (buffer last read in interval k-1 -> safe after barrier_k)
        if (ks + 2 < ksteps) {
            unsigned short* dA0 = lA0 + pbuf * 4096;
            unsigned short* dA1 = lA1 + pbuf * 4096;
            unsigned short* dB0 = lB0 + pbuf * 4096;
            unsigned short* dB1 = lB1 + pbuf * 4096;
            gld16(pA0, dA0); gld16(pA1, dA1); gld16(pB0, dB0); gld16(pB1, dB1);
            pA0 += 32; pA1 += 32; pB0 += 32; pB1 += 32;
            pbuf = (pbuf == 2) ? 0 : pbuf + 1;
        }
        const unsigned short* as = As + buf * 4096;
        const unsigned short* bs = Bs + buf * 4096;
        short8 af[4], bfr[4];
        #pragma unroll
        for (int i = 0; i < 4; ++i) {
            af[i]  = *(const short8*)&as[offA[i]];
            bfr[i] = *(const short8*)&bs[offB[i]];
        }
        #pragma unroll
        for (int i = 0; i < 4; ++i)
            #pragma unroll
            for (int j = 0; j < 4; ++j)
                acc[i][j] = __builtin_amdgcn_mfma_f32_16x16x32_bf16(af[i], bfr[j], acc[i][j], 0, 0, 0);
        buf = (buf == 2) ? 0 : buf + 1;
    }
    const int cr = (lane >> 4) * 4;
    const int cc = lane & 15;
    #pragma unroll
    for (int i = 0; i < 4; ++i) {
        #pragma unroll
        for (int r = 0; r < 4; ++r) {
            int m = m0 + wm + i * 16 + cr + r;
            if (m >= NN) continue;
            #pragma unroll
            for (int j = 0; j < 4; ++j) {
                int n = n0 + wn + j * 16 + cc;
                if (n >= nvalid) continue;
                if (mode == 1) {
                    int g = n >> 6, h = n & 63;
                    C[(size_t)g * NN * NH + (size_t)m * NH + h] = __float2bfloat16(acc[i][j][r]);
                } else {
                    int g = n / NC, c = n - g * NC;
                    C[(size_t)g * NN * NC + (size_t)m * NC + c] = __float2bfloat16(acc[i][j][r]);
                }
            }
        }
    }
}

// ---------------- SPMM1: branch-pinned blocks (g = bid % CHk -> XCD), 2 nodes/wave ----------------
__global__ __launch_bounds__(256) void spmm1_kernel(const bf16* __restrict__ sup,
                                                    const int* __restrict__ offs,
                                                    const unsigned* __restrict__ sedge,
                                                    const float* __restrict__ b1,
                                                    bf16* __restrict__ h1cat, int d0, int CHk) {
    const int i = blockIdx.x;
    const int g = i % CHk;
    const int nb = i / CHk;
    const int tid = threadIdx.x;
    const int lane = tid & 63;
    const int n = nb * 8 + ((tid >> 6) << 1) + (lane >> 5);
    const int hl = lane & 31;
    const int d = d0 + g;
    const int s = offs[d * (NN + 1) + n];
    const int e = offs[d * (NN + 1) + n + 1];
    const char* supd = (const char*)sup + (size_t)g * NN * NH * 2;
    const unsigned* sed = sedge + (size_t)d * NE;
    const unsigned hoff = (unsigned)hl * 4;
    float alo0 = 0.f, ahi0 = 0.f, alo1 = 0.f, ahi1 = 0.f;
    int j = s;
    for (; j + 4 <= e; j += 4) {
        unsigned e0 = sed[j], e1 = sed[j + 1], e2 = sed[j + 2], e3 = sed[j + 3];
        unsigned w0 = *(const unsigned*)(supd + (((e0 & 0xFFFFu) << 7) | hoff));
        unsigned w1 = *(const unsigned*)(supd + (((e1 & 0xFFFFu) << 7) | hoff));
        unsigned w2 = *(const unsigned*)(supd + (((e2 & 0xFFFFu) << 7) | hoff));
        unsigned w3 = *(const unsigned*)(supd + (((e3 & 0xFFFFu) << 7) | hoff));
        float v0 = bhi(e0), v1 = bhi(e1), v2 = bhi(e2), v3 = bhi(e3);
        alo0 = fmaf(v0, blo(w0), alo0); ahi0 = fmaf(v0, bhi(w0), ahi0);
        alo1 = fmaf(v1, blo(w1), alo1); ahi1 = fmaf(v1, bhi(w1), ahi1);
        alo0 = fmaf(v2, blo(w2), alo0); ahi0 = fmaf(v2, bhi(w2), ahi0);
        alo1 = fmaf(v3, blo(w3), alo1); ahi1 = fmaf(v3, bhi(w3), ahi1);
    }
    for (; j < e; ++j) {
        unsigned e0 = sed[j];
        unsigned w0 = *(const unsigned*)(supd + (((e0 & 0xFFFFu) << 7) | hoff));
        float v0 = bhi(e0);
        alo0 = fmaf(v0, blo(w0), alo0); ahi0 = fmaf(v0, bhi(w0), ahi0);
    }
    float alo = fmaxf((alo0 + alo1) + b1[d * NH + 2 * hl], 0.f);
    float ahi = fmaxf((ahi0 + ahi1) + b1[d * NH + 2 * hl + 1], 0.f);
    unsigned packed = bf16bits(alo) | (bf16bits(ahi) << 16);
    *(unsigned*)((char*)h1cat + ((size_t)n * K2 + d * NH) * 2 + hoff) = packed;
}

// ---------------- SPMM2 stage 1: branch d pinned to XCD d%8 (d=24 spread), relu'd bf16x2 ----------------
__global__ __launch_bounds__(256) void spmm2b_kernel(const bf16* __restrict__ sup2,
                                                     const int* __restrict__ offs,
                                                     const unsigned* __restrict__ sedge,
                                                     const float* __restrict__ b2,
                                                     unsigned* __restrict__ h2u) {
    const int i = blockIdx.x;
    const int r = i & 7;
    const int q = i >> 3;           // [0, 7813)
    int d, nb;
    if (q < 7500) { d = r + 8 * (q / 2500); nb = q % 2500; }
    else { d = 24; nb = (q - 7500) * 8 + r; if (nb >= 2500) return; }
    const int tid = threadIdx.x;
    const int lane = tid & 63;
    const int n = nb * 8 + ((tid >> 6) << 1) + (lane >> 5);
    const int cl = min(lane & 31, 24);      // class pair 2cl,2cl+1; lanes 25-31 dup
    const unsigned coff = (unsigned)cl * 4;
    const int s = offs[d * (NN + 1) + n];
    const int e = offs[d * (NN + 1) + n + 1];
    const char* supd = (const char*)sup2 + (size_t)d * NN * NC * 2;
    const unsigned* sed = sedge + (size_t)d * NE;
    float alo0 = b2[d * NC + 2 * cl], ahi0 = b2[d * NC + 2 * cl + 1];
    float alo1 = 0.f, ahi1 = 0.f;
    int j = s;
    for (; j + 4 <= e; j += 4) {
        unsigned e0 = sed[j], e1 = sed[j + 1], e2 = sed[j + 2], e3 = sed[j + 3];
        unsigned w0 = *(const unsigned*)(supd + ((e0 & 0xFFFFu) * 100u + coff));
        unsigned w1 = *(const unsigned*)(supd + ((e1 & 0xFFFFu) * 100u + coff));
        unsigned w2 = *(const unsigned*)(supd + ((e2 & 0xFFFFu) * 100u + coff));
        unsigned w3 = *(const unsigned*)(supd + ((e3 & 0xFFFFu) * 100u + coff));
        float v0 = bhi(e0), v1 = bhi(e1), v2 = bhi(e2), v3 = bhi(e3);
        alo0 = fmaf(v0, blo(w0), alo0); ahi0 = fmaf(v0, bhi(w0), ahi0);
        alo1 = fmaf(v1, blo(w1), alo1); ahi1 = fmaf(v1, bhi(w1), ahi1);
        alo0 = fmaf(v2, blo(w2), alo0); ahi0 = fmaf(v2, bhi(w2), ahi0);
        alo1 = fmaf(v3, blo(w3), alo1); ahi1 = fmaf(v3, bhi(w3), ahi1);
    }
    for (; j < e; ++j) {
        unsigned e0 = sed[j];
        unsigned w0 = *(const unsigned*)(supd + ((e0 & 0xFFFFu) * 100u + coff));
        float v0 = bhi(e0);
        alo0 = fmaf(v0, blo(w0), alo0); ahi0 = fmaf(v0, bhi(w0), ahi0);
    }
    float alo = fmaxf(alo0 + alo1, 0.f);
    float ahi = fmaxf(ahi0 + ahi1, 0.f);
    if ((lane & 31) < 25)
        h2u[((size_t)d * NN + n) * 25 + cl] = bf16bits(alo) | (bf16bits(ahi) << 16);
}

// ---------------- SPMM2 stage 2: streaming max over branches ----------------
__global__ __launch_bounds__(256) void maxk_kernel(const unsigned* __restrict__ h2u,
                                                   float* __restrict__ out) {
    int i = blockIdx.x * blockDim.x + threadIdx.x;   // [0, NN*25)
    if (i >= NN * 25) return;
    int n = i / 25, cl = i - n * 25;
    float mlo = 0.f, mhi = 0.f;
    #pragma unroll
    for (int d = 0; d < DIM; ++d) {
        unsigned w = h2u[(size_t)d * NN * 25 + i];
        mlo = fmaxf(mlo, blo(w));
        mhi = fmaxf(mhi, bhi(w));
    }
    *(float2*)&out[(size_t)n * NC + 2 * cl] = make_float2(mlo, mhi);
}

extern "C" void kernel_launch(void* const* d_in, const int* in_sizes, int n_in,
                              void* d_out, int out_size, void* d_ws, size_t ws_size,
                              hipStream_t stream) {
    const float* x    = (const float*)d_in[0];
    const int*   rows = (const int*)d_in[1];
    const int*   cols = (const int*)d_in[2];
    const float* vals = (const float*)d_in[3];
    const float* W1   = (const float*)d_in[4];
    const float* b1   = (const float*)d_in[5];
    const float* W2   = (const float*)d_in[6];
    const float* b2   = (const float*)d_in[7];
    float* out = (float*)d_out;

    char* ws = (char*)d_ws;
    size_t off = 0;
    auto alloc = [&](size_t bytes) {
        void* p = ws + off;
        off += (bytes + 255) & ~(size_t)255;
        return p;
    };
    bf16* supbuf = (bf16*)alloc(sizeof(bf16) * (size_t)DIM * NN * NC);   // 50 MB
    bf16* h1cat  = (bf16*)alloc(sizeof(bf16) * (size_t)NN * K2);         // 64 MB (aliases inter & h2)
    bf16* b1t    = (bf16*)alloc(sizeof(bf16) * (size_t)B1T_ROWS * KP1);  // 1.07 MB
    bf16* b2t    = (bf16*)alloc(sizeof(bf16) * (size_t)B2T_ROWS * K2);   // 4.1 MB
    int*  offs   = (int*)alloc(sizeof(int) * (size_t)DIM * (NN + 1));    // 2 MB
    int*  gcur   = (int*)alloc(sizeof(int) * (size_t)DIM * NBK);
    int*  offs_b = (int*)alloc(sizeof(int) * (size_t)DIM * NBK);
    int*  bcnt   = (int*)alloc(sizeof(int) * (size_t)DIM * NBK);
    unsigned* sedge = (unsigned*)alloc(sizeof(unsigned) * (size_t)DIM * NE); // 32 MB

    bf16* sup1 = supbuf;                                   // [<=8][NN][64] = 20.5 MB
    bf16* xbf  = supbuf + (size_t)12 * 1024 * 1024;        // +24 MB (12.8 MB)
    bf16* sup2 = supbuf;                                   // [25][NN][50]
    unsigned* interE = (unsigned*)h1cat;
    unsigned char* interR = (unsigned char*)h1cat + (size_t)DIM * NBK * FCAP * 4;
    unsigned* h2u = (unsigned*)h1cat;                      // 50 MB, h1cat dead after gemm2

    if (off > ws_size) return;  // diagnostic guard (~153 MB, known-safe)

    // CSR build
    zero_kernel<<<(DIM * NBK + 255) / 256, 256, 0, stream>>>(gcur, DIM * NBK);
    bucket_scatter_kernel<<<dim3(BPB, DIM), 256, 0, stream>>>(rows, cols, vals, gcur, interE, interR);
    bucket_scan_kernel<<<DIM, 64, 0, stream>>>(gcur, offs_b, bcnt, offs);
    csr_finalize_kernel<<<dim3(NBK, DIM), 256, 0, stream>>>(interE, interR, offs_b, bcnt, offs, sedge);

    // Packing
    pack_x_kernel<<<(NN * KP1 + 255) / 256, 256, 0, stream>>>(x, xbf);
    pack_b1_kernel<<<(B1T_ROWS * KP1 + 255) / 256, 256, 0, stream>>>(W1, b1t);
    pack_b2_kernel<<<(B2T_ROWS * K2 + 255) / 256, 256, 0, stream>>>(W2, b2t);

    const int mtiles = (NN + 127) / 128;  // 157

    // Layer 1: chunks of {8,8,8,1} branches (branch -> XCD pinning in spmm1)
    const int cstart[4] = {0, 8, 16, 24};
    const int csize[4]  = {8, 8, 8, 1};
    const int crow[4]   = {0, 512, 1024, 1536};
    for (int c = 0; c < 4; ++c) {
        int nv = csize[c] * 64;
        gemm_bf16_kernel<<<dim3(mtiles, (nv + 127) / 128), 256, 0, stream>>>(
            xbf, KP1, b1t + (size_t)crow[c] * KP1, KP1, sup1, KP1 / 32, 1, nv);
        spmm1_kernel<<<csize[c] * (NN / 8), 256, 0, stream>>>(
            sup1, offs, sedge, b1, h1cat, cstart[c], csize[c]);
    }
    // Layer 2: GEMM [20000x1600]@[1600x1280] -> sup2; branch-pinned spmm2 -> h2; max -> out
    gemm_bf16_kernel<<<dim3(mtiles, B2T_ROWS / 128), 256, 0, stream>>>(
        h1cat, K2, b2t, K2, sup2, K2 / 32, 2, DIM * NC);
    spmm2b_kernel<<<8 * 7813, 256, 0, stream>>>(sup2, offs, sedge, b2, h2u);
    maxk_kernel<<<(NN * 25 + 255) / 256, 256, 0, stream>>>(h2u, out);
}

// Round 3
// 727.764 us; speedup vs baseline: 1.0701x; 1.0381x over previous
//
#include <hip/hip_runtime.h>
#include <hip/hip_bf16.h>
#include <cstdint>
#include <cstddef>

#define DIM 25
#define NN 20000
#define NE 320000
#define NF 300
#define NH 64
#define NC 50
#define K2 (DIM*NH)   // 1600
#define KP1 320       // layer-1 K padded (300 -> 320)
#define B1T_ROWS 1664 // chunks {8,8,8,1} branches -> {512,512,512,128} rows
#define B2T_ROWS 1280 // 25*50=1250 padded to 10*128
#define NBK 79        // row buckets of 256 rows
#define EPB 4096      // edges per binning block
#define BPB ((NE + EPB - 1) / EPB)  // 79
#define FCAP 5632     // fixed bucket slot capacity (mean 4096 + 24 sigma)

typedef __attribute__((ext_vector_type(8))) short short8;
typedef __attribute__((ext_vector_type(4))) float floatx4;
typedef __hip_bfloat16 bf16;

static __device__ __forceinline__ unsigned bf16bits(float f) {
    bf16 b = __float2bfloat16(f);
    return (unsigned)*reinterpret_cast<unsigned short*>(&b);
}
static __device__ __forceinline__ float blo(unsigned w) { return __uint_as_float(w << 16); }
static __device__ __forceinline__ float bhi(unsigned w) { return __uint_as_float(w & 0xFFFF0000u); }

// async global->LDS, 16B per lane; LDS dest = wave-uniform base + lane*16
static __device__ __forceinline__ void gld16(const void* g, void* l) {
    __builtin_amdgcn_global_load_lds((const __attribute__((address_space(1))) unsigned*)g,
                                     (__attribute__((address_space(3))) unsigned*)l, 16, 0, 0);
}
// LDS byte offset of a __shared__ pointer (low 32 bits of the shared aperture address)
static __device__ __forceinline__ unsigned lds_off(const void* p) {
    return (unsigned)(size_t)(const __attribute__((address_space(3))) char*)p;
}
// inline-asm ds_read_b128: opaque to SIInsertWaitcnts (no compiler vmcnt/lgkm drains)
#define DSR(dst, a, off) asm volatile("ds_read_b128 %0, %1 offset:" #off : "=v"(dst) : "v"(a))

// ---------------- utility ----------------
__global__ void zero_kernel(int* __restrict__ p, int n) {
    int i = blockIdx.x * blockDim.x + threadIdx.x;
    if (i < n) p[i] = 0;
}

// ---------------- CSR build ----------------
__global__ __launch_bounds__(256) void bucket_scatter_kernel(const int* __restrict__ rows,
                                                             const int* __restrict__ cols,
                                                             const float* __restrict__ vals,
                                                             int* __restrict__ gcur,
                                                             unsigned* __restrict__ interE,
                                                             unsigned char* __restrict__ interR) {
    const int d = blockIdx.y;
    const int e0 = blockIdx.x * EPB;
    __shared__ int lh[NBK];
    __shared__ int lo[NBK];
    __shared__ int lbase[NBK];
    __shared__ unsigned entE[EPB];        // 16 KB
    __shared__ unsigned short entR[EPB];  // 8 KB
    const int tid = threadIdx.x;
    for (int i = tid; i < NBK; i += 256) lh[i] = 0;
    __syncthreads();
    const int* rd = rows + (size_t)d * NE;
    const int* cd = cols + (size_t)d * NE;
    const float* vd = vals + (size_t)d * NE;
    const int e1 = min(e0 + EPB, NE);
    const int ne = e1 - e0;
    for (int i = e0 + tid; i < e1; i += 256)
        atomicAdd(&lh[rd[i] >> 8], 1);
    __syncthreads();
    if (tid == 0) {
        int run = 0;
        for (int b = 0; b < NBK; ++b) { lo[b] = run; run += lh[b]; }
    }
    __syncthreads();
    for (int i = tid; i < NBK; i += 256) {
        lbase[i] = lh[i] ? atomicAdd(&gcur[d * NBK + i], lh[i]) : 0;
        lh[i] = 0;
    }
    __syncthreads();
    for (int i = e0 + tid; i < e1; i += 256) {
        int r = rd[i];
        int b = r >> 8;
        int rank = atomicAdd(&lh[b], 1);
        int pos = lo[b] + rank;
        entE[pos] = (unsigned)cd[i] | (bf16bits(vd[i]) << 16);
        entR[pos] = (unsigned short)r;
    }
    __syncthreads();
    for (int p = tid; p < ne; p += 256) {
        int r = entR[p];
        int b = r >> 8;
        int gpos = lbase[b] + (p - lo[b]);
        if (gpos < FCAP) {
            size_t slot = ((size_t)d * NBK + b) * FCAP + gpos;
            interE[slot] = entE[p];
            interR[slot] = (unsigned char)r;
        }
    }
}

__global__ void bucket_scan_kernel(const int* __restrict__ gcur,
                                   int* __restrict__ offs_b,
                                   int* __restrict__ bcnt,
                                   int* __restrict__ offs) {
    const int d = blockIdx.x;
    if (threadIdx.x != 0) return;
    int run = 0;
    for (int b = 0; b < NBK; ++b) {
        int c = min(gcur[d * NBK + b], FCAP);
        offs_b[d * NBK + b] = run;
        bcnt[d * NBK + b] = c;
        run += c;
    }
    offs[d * (NN + 1) + NN] = run;
}

__global__ __launch_bounds__(256) void csr_finalize_kernel(const unsigned* __restrict__ interE,
                                                           const unsigned char* __restrict__ interR,
                                                           const int* __restrict__ offs_b,
                                                           const int* __restrict__ bcnt,
                                                           int* __restrict__ offs,
                                                           unsigned* __restrict__ sedge) {
    const int d = blockIdx.y;
    const int b = blockIdx.x;
    const int tid = threadIdx.x;
    const int s = offs_b[d * NBK + b];
    const int cnt = bcnt[d * NBK + b];
    const size_t base = ((size_t)d * NBK + b) * FCAP;
    __shared__ int sm[256];
    __shared__ int cur[256];
    __shared__ unsigned lse[FCAP];  // 22 KB
    sm[tid] = 0;
    __syncthreads();
    for (int i = tid; i < cnt; i += 256)
        atomicAdd(&sm[interR[base + i]], 1);
    __syncthreads();
    int own = sm[tid];
    for (int off = 1; off < 256; off <<= 1) {
        int t = (tid >= off) ? sm[tid - off] : 0;
        __syncthreads();
        sm[tid] += t;
        __syncthreads();
    }
    int excl = sm[tid] - own;
    int row = (b << 8) + tid;
    if (row < NN) offs[d * (NN + 1) + row] = s + excl;
    cur[tid] = excl;
    __syncthreads();
    for (int i = tid; i < cnt; i += 256) {
        int idx = atomicAdd(&cur[interR[base + i]], 1);
        lse[idx] = interE[base + i];
    }
    __syncthreads();
    unsigned* sed = sedge + (size_t)d * NE;
    for (int t = tid; t < cnt; t += 256)
        sed[s + t] = lse[t];
}

// ---------------- packing ----------------
__global__ void pack_x_kernel(const float* __restrict__ x, bf16* __restrict__ xb) {
    int i = blockIdx.x * blockDim.x + threadIdx.x;
    if (i >= NN * KP1) return;
    int n = i / KP1, k = i - n * KP1;
    xb[i] = __float2bfloat16((k < NF) ? x[(size_t)n * NF + k] : 0.f);
}

// chunks {8,8,8,1}: chunk c rows [c*512, ...), row r -> branch c*8 + (r>>6), h = r&63
__global__ void pack_b1_kernel(const float* __restrict__ W1, bf16* __restrict__ b1t) {
    int i = blockIdx.x * blockDim.x + threadIdx.x;
    if (i >= B1T_ROWS * KP1) return;
    int j2 = i / KP1, k = i - j2 * KP1;
    int chunk = j2 >> 9;
    int r = j2 & 511;
    int d = chunk * 8 + (r >> 6);
    float v = 0.f;
    if (d < DIM && k < NF)
        v = W1[(size_t)d * NF * NH + (size_t)k * NH + (r & 63)];
    b1t[i] = __float2bfloat16(v);
}

__global__ void pack_b2_kernel(const float* __restrict__ W2, bf16* __restrict__ b2t) {
    int i = blockIdx.x * blockDim.x + threadIdx.x;
    if (i >= B2T_ROWS * K2) return;
    int r = i / K2, k = i - r * K2;
    float v = 0.f;
    if (r < DIM * NC) {
        int g = r / NC, c = r - g * NC;
        v = W2[(size_t)g * K2 * NC + (size_t)k * NC + c];
    }
    b2t[i] = __float2bfloat16(v);
}

// ======== 256x256 BK=64 8-wave phase-interleaved GEMM (T2+T3+T4+T5 port of m201) ========
// 8 waves as 2(M)x4(N); per-wave 128x64 out = acc[8][4] f32x4. LDS 2buf x (A 32KB + B 32KB).
// LDS tile [256 rows][8 slots of 16B], slot XOR-swizzled: LDS[r][s] = G[r][s ^ (r&7)]
// (pre-swizzled global source, linear gld_lds dest, swizzled asm ds_read -- rule #21).
// Per K-tile, 4 phases {asm ds_read subtile | gld16 prefetch of tile kt+1 | lgkmcnt(0) |
// sched_barrier | setprio(1) 16 MFMA setprio(0)}; ONE vmcnt(0)+s_barrier per tile
// (prefetch issued 2-3 phases before the wait -> latency covered; no per-phase drain).
__global__ __launch_bounds__(512, 2) void gemm256_bf16_kernel(const bf16* __restrict__ A, int lda,
                                                              const bf16* __restrict__ BT, int ldb,
                                                              bf16* __restrict__ C,
                                                              int ktiles, int mode, int nvalid) {
    __shared__ unsigned short As[2 * 256 * 64];   // 64 KB
    __shared__ unsigned short Bs[2 * 256 * 64];   // 64 KB
    const int tid = threadIdx.x;
    const int w = tid >> 6;
    const int l = tid & 63;
    // grouped raster: n fastest within groups of 8 m-tiles (A-panel L2 resident)
    const int MT = (int)gridDim.x;
    const int NT = (int)gridDim.y;
    const int bid = (int)blockIdx.y * MT + (int)blockIdx.x;
    const int pg = 8 * NT;
    const int grp = bid / pg;
    const int rem = bid - grp * pg;
    const int fm = grp * 8;
    const int gm = min(8, MT - fm);
    const int mt = fm + rem % gm;
    const int nt = rem / gm;
    const int m0 = mt * 256, n0 = nt * 256;
    const int wr = w >> 2, wc = w & 3;

    floatx4 acc[8][4] = {};

    // staging: 4 q-blocks of 64 rows each per operand; thread -> row w*8+(l>>3), chunk (l&7)^(l>>3)
    const int strow = w * 8 + (l >> 3);
    const int gch = (l & 7) ^ (l >> 3);
    const bf16* pA[4];
    const bf16* pB[4];
    #pragma unroll
    for (int q = 0; q < 4; ++q) {
        pA[q] = A + (size_t)(m0 + q * 64 + strow) * lda + gch * 8;
        pB[q] = BT + (size_t)(n0 + q * 64 + strow) * ldb + gch * 8;
    }
    // asm ds_read bases: row = (wr*128 | wc*64) + frag*16 + (l&15); slot = kf*4 + (l>>4), ^ (l&7)
    const unsigned slc0 = (unsigned)(((l >> 4)) ^ (l & 7)) * 16u;
    const unsigned slc1 = (unsigned)((4 + (l >> 4)) ^ (l & 7)) * 16u;
    const unsigned aRow = (unsigned)(wr * 128 + (l & 15)) * 128u;
    const unsigned bRow = (unsigned)(wc * 64 + (l & 15)) * 128u;
    const unsigned ldsA = lds_off(As), ldsB = lds_off(Bs);

    // prologue: stage K-tile 0 into buffer 0
    #pragma unroll
    for (int q = 0; q < 4; ++q) { gld16(pA[q], As + q * 4096 + w * 512); pA[q] += 64; }
    #pragma unroll
    for (int q = 0; q < 4; ++q) { gld16(pB[q], Bs + q * 4096 + w * 512); pB[q] += 64; }
    asm volatile("s_waitcnt vmcnt(0)");
    __builtin_amdgcn_sched_barrier(0);
    __builtin_amdgcn_s_barrier();
    __builtin_amdgcn_sched_barrier(0);

    short8 aF[4][2], bF[4][2];
    for (int kt = 0; kt < ktiles; ++kt) {
        const int c = kt & 1;
        const unsigned boff = (unsigned)c * 32768u;
        const unsigned aA0 = ldsA + boff + aRow + slc0;
        const unsigned aA1 = ldsA + boff + aRow + slc1;
        const unsigned bA0 = ldsB + boff + bRow + slc0;
        const unsigned bA1 = ldsB + boff + bRow + slc1;
        unsigned short* nA = As + (c ^ 1) * 16384 + w * 512;
        unsigned short* nB = Bs + (c ^ 1) * 16384 + w * 512;
        const bool stage = (kt + 1 < ktiles);
        // ---------- phase 1: read A[mh0] + B[nh0], prefetch next A ----------
        DSR(aF[0][0], aA0, 0);    DSR(aF[0][1], aA1, 0);
        DSR(aF[1][0], aA0, 2048); DSR(aF[1][1], aA1, 2048);
        DSR(aF[2][0], aA0, 4096); DSR(aF[2][1], aA1, 4096);
        DSR(aF[3][0], aA0, 6144); DSR(aF[3][1], aA1, 6144);
        DSR(bF[0][0], bA0, 0);    DSR(bF[0][1], bA1, 0);
        DSR(bF[1][0], bA0, 2048); DSR(bF[1][1], bA1, 2048);
        if (stage) {
            gld16(pA[0], nA);         gld16(pA[1], nA + 4096);
            gld16(pA[2], nA + 8192);  gld16(pA[3], nA + 12288);
            pA[0] += 64; pA[1] += 64; pA[2] += 64; pA[3] += 64;
        }
        asm volatile("s_waitcnt lgkmcnt(0)");
        __builtin_amdgcn_sched_barrier(0);
        __builtin_amdgcn_s_setprio(1);
        #pragma unroll
        for (int mf = 0; mf < 4; ++mf)
            #pragma unroll
            for (int nf = 0; nf < 2; ++nf) {
                acc[mf][nf] = __builtin_amdgcn_mfma_f32_16x16x32_bf16(aF[mf][0], bF[nf][0], acc[mf][nf], 0, 0, 0);
                acc[mf][nf] = __builtin_amdgcn_mfma_f32_16x16x32_bf16(aF[mf][1], bF[nf][1], acc[mf][nf], 0, 0, 0);
            }
        __builtin_amdgcn_s_setprio(0);
        __builtin_amdgcn_sched_barrier(0);
        // ---------- phase 2: read B[nh1], prefetch next B ----------
        DSR(bF[2][0], bA0, 4096); DSR(bF[2][1], bA1, 4096);
        DSR(bF[3][0], bA0, 6144); DSR(bF[3][1], bA1, 6144);
        if (stage) {
            gld16(pB[0], nB);         gld16(pB[1], nB + 4096);
            gld16(pB[2], nB + 8192);  gld16(pB[3], nB + 12288);
            pB[0] += 64; pB[1] += 64; pB[2] += 64; pB[3] += 64;
        }
        asm volatile("s_waitcnt lgkmcnt(0)");
        __builtin_amdgcn_sched_barrier(0);
        __builtin_amdgcn_s_setprio(1);
        #pragma unroll
        for (int mf = 0; mf < 4; ++mf)
            #pragma unroll
            for (int nf = 2; nf < 4; ++nf) {
                acc[mf][nf] = __builtin_amdgcn_mfma_f32_16x16x32_bf16(aF[mf][0], bF[nf][0], acc[mf][nf], 0, 0, 0);
                acc[mf][nf] = __builtin_amdgcn_mfma_f32_16x16x32_bf16(aF[mf][1], bF[nf][1], acc[mf][nf], 0, 0, 0);
            }
        __builtin_amdgcn_s_setprio(0);
        __builtin_amdgcn_sched_barrier(0);
        // ---------- phase 3: read A[mh1] (reuse regs) ----------
        DSR(aF[0][0], aA0, 8192);  DSR(aF[0][1], aA1, 8192);
        DSR(aF[1][0], aA0, 10240); DSR(aF[1][1], aA1, 10240);
        DSR(aF[2][0], aA0, 12288); DSR(aF[2][1], aA1, 12288);
        DSR(aF[3][0], aA0, 14336); DSR(aF[3][1], aA1, 14336);
        asm volatile("s_waitcnt lgkmcnt(0)");
        __builtin_amdgcn_sched_barrier(0);
        __builtin_amdgcn_s_setprio(1);
        #pragma unroll
        for (int mf = 0; mf < 4; ++mf)
            #pragma unroll
            for (int nf = 2; nf < 4; ++nf) {
                acc[mf + 4][nf] = __builtin_amdgcn_mfma_f32_16x16x32_bf16(aF[mf][0], bF[nf][0], acc[mf + 4][nf], 0, 0, 0);
                acc[mf + 4][nf] = __builtin_amdgcn_mfma_f32_16x16x32_bf16(aF[mf][1], bF[nf][1], acc[mf + 4][nf], 0, 0, 0);
            }
        __builtin_amdgcn_s_setprio(0);
        __builtin_amdgcn_sched_barrier(0);
        // ---------- phase 4: MFMA only ----------
        __builtin_amdgcn_s_setprio(1);
        #pragma unroll
        for (int mf = 0; mf < 4; ++mf)
            #pragma unroll
            for (int nf = 0; nf < 2; ++nf) {
                acc[mf + 4][nf] = __builtin_amdgcn_mfma_f32_16x16x32_bf16(aF[mf][0], bF[nf][0], acc[mf + 4][nf], 0, 0, 0);
                acc[mf + 4][nf] = __builtin_amdgcn_mfma_f32_16x16x32_bf16(aF[mf][1], bF[nf][1], acc[mf + 4][nf], 0, 0, 0);
            }
        __builtin_amdgcn_s_setprio(0);
        __builtin_amdgcn_sched_barrier(0);
        // ---------- tile boundary: next buffer staged, all reads of cur done ----------
        if (stage) {
            asm volatile("s_waitcnt vmcnt(0)");
            __builtin_amdgcn_sched_barrier(0);
            __builtin_amdgcn_s_barrier();
            __builtin_amdgcn_sched_barrier(0);
        }
    }
    // epilogue
    const int cr = (l >> 4) * 4;
    const int cc = l & 15;
    #pragma unroll
    for (int mf = 0; mf < 8; ++mf) {
        #pragma unroll
        for (int r = 0; r < 4; ++r) {
            int m = m0 + wr * 128 + mf * 16 + cr + r;
            if (m >= NN) continue;
            #pragma unroll
            for (int nf = 0; nf < 4; ++nf) {
                int n = n0 + wc * 64 + nf * 16 + cc;
                if (n >= nvalid) continue;
                if (mode == 1) {
                    int g = n >> 6, h = n & 63;
                    C[(size_t)g * NN * NH + (size_t)m * NH + h] = __float2bfloat16(acc[mf][nf][r]);
                } else {
                    int g = n / NC, cl2 = n - g * NC;
                    C[(size_t)g * NN * NC + (size_t)m * NC + cl2] = __float2bfloat16(acc[mf][nf][r]);
                }
            }
        }
    }
}

// ---------------- legacy 128^2 GEMM (kept for the 64-col layer-1 chunk) ----------------
__global__ __launch_bounds__(256) void gemm_bf16_kernel(const bf16* __restrict__ A, int lda,
                                                        const bf16* __restrict__ BT, int ldb,
                                                        bf16* __restrict__ C,
                                                        int ksteps, int mode, int nvalid) {
    __shared__ unsigned short As[3 * 128 * 32];
    __shared__ unsigned short Bs[3 * 128 * 32];
    const int tid = threadIdx.x;
    const int wave = tid >> 6;
    const int lane = tid & 63;
    const int mtiles = (int)gridDim.x;
    const int ntiles = (int)gridDim.y;
    const int bid = (int)blockIdx.y * mtiles + (int)blockIdx.x;
    const int per_group = 8 * ntiles;
    const int group = bid / per_group;
    const int rem = bid - group * per_group;
    const int first_m = group * 8;
    const int gm = min(8, mtiles - first_m);
    const int mt = first_m + rem % gm;
    const int nt = rem / gm;
    const int m0 = mt * 128;
    const int n0 = nt * 128;
    const int wm = (wave >> 1) * 64;
    const int wn = (wave & 1) * 64;
    floatx4 acc[4][4] = {};
    const int r0 = tid >> 2;
    const int cg = (tid & 3) ^ ((r0 >> 1) & 3);
    const int q8 = (lane >> 4) * 8;
    const int gq = q8 >> 3;
    unsigned short* lA0 = As + wave * 512;
    unsigned short* lA1 = As + 2048 + wave * 512;
    unsigned short* lB0 = Bs + wave * 512;
    unsigned short* lB1 = Bs + 2048 + wave * 512;
    const bf16* gA0 = A + (size_t)(m0 + r0) * lda + cg * 8;
    const bf16* gA1 = A + (size_t)(m0 + r0 + 64) * lda + cg * 8;
    const bf16* gB0 = BT + (size_t)(n0 + r0) * ldb + cg * 8;
    const bf16* gB1 = BT + (size_t)(n0 + r0 + 64) * ldb + cg * 8;
    int offA[4], offB[4];
    #pragma unroll
    for (int i = 0; i < 4; ++i) {
        int ra = wm + i * 16 + (lane & 15);
        int rb = wn + i * 16 + (lane & 15);
        offA[i] = ra * 32 + ((gq ^ ((ra >> 1) & 3)) << 3);
        offB[i] = rb * 32 + ((gq ^ ((rb >> 1) & 3)) << 3);
    }
    gld16(gA0, lA0); gld16(gA1, lA1); gld16(gB0, lB0); gld16(gB1, lB1);
    if (ksteps > 1) {
        gld16(gA0 + 32, lA0 + 4096); gld16(gA1 + 32, lA1 + 4096);
        gld16(gB0 + 32, lB0 + 4096); gld16(gB1 + 32, lB1 + 4096);
    }
    const bf16* pA0 = gA0 + 64;
    const bf16* pA1 = gA1 + 64;
    const bf16* pB0 = gB0 + 64;
    const bf16* pB1 = gB1 + 64;
    int buf = 0;
    int pbuf = 2;
    for (int ks = 0; ks < ksteps; ++ks) {
        if (ks + 1 < ksteps) asm volatile("s_waitcnt vmcnt(4)" ::: "memory");
        else                 asm volatile("s_waitcnt vmcnt(0)" ::: "memory");
        __builtin_amdgcn_sched_barrier(0);
        __builtin_amdgcn_s_barrier();
        __builtin_amdgcn_sched_barrier(0);
        if (ks + 2 < ksteps) {
            unsigned short* dA0 = lA0 + pbuf * 4096;
            unsigned short* dA1 = lA1 + pbuf * 4096;
            unsigned short* dB0 = lB0 + pbuf * 4096;
            unsigned short* dB1 = lB1 + pbuf * 4096;
            gld16(pA0, dA0); gld16(pA1, dA1); gld16(pB0, dB0); gld16(pB1, dB1);
            pA0 += 32; pA1 += 32; pB0 += 32; pB1 += 32;
            pbuf = (pbuf == 2) ? 0 : pbuf + 1;
        }
        const unsigned short* as = As + buf * 4096;
        const unsigned short* bs = Bs + buf * 4096;
        short8 af[4], bfr[4];
        #pragma unroll
        for (int i = 0; i < 4; ++i) {
            af[i]  = *(const short8*)&as[offA[i]];
            bfr[i] = *(const short8*)&bs[offB[i]];
        }
        #pragma unroll
        for (int i = 0; i < 4; ++i)
            #pragma unroll
            for (int j = 0; j < 4; ++j)
                acc[i][j] = __builtin_amdgcn_mfma_f32_16x16x32_bf16(af[i], bfr[j], acc[i][j], 0, 0, 0);
        buf = (buf == 2) ? 0 : buf + 1;
    }
    const int cr = (lane >> 4) * 4;
    const int cc = lane & 15;
    #pragma unroll
    for (int i = 0; i < 4; ++i) {
        #pragma unroll
        for (int r = 0; r < 4; ++r) {
            int m = m0 + wm + i * 16 + cr + r;
            if (m >= NN) continue;
            #pragma unroll
            for (int j = 0; j < 4; ++j) {
                int n = n0 + wn + j * 16 + cc;
                if (n >= nvalid) continue;
                if (mode == 1) {
                    int g = n >> 6, h = n & 63;
                    C[(size_t)g * NN * NH + (size_t)m * NH + h] = __float2bfloat16(acc[i][j][r]);
                } else {
                    int g = n / NC, c = n - g * NC;
                    C[(size_t)g * NN * NC + (size_t)m * NC + c] = __float2bfloat16(acc[i][j][r]);
                }
            }
        }
    }
}

// ---------------- SPMM1: branch-pinned blocks (g = bid % CHk -> XCD), 2 nodes/wave ----------------
__global__ __launch_bounds__(256) void spmm1_kernel(const bf16* __restrict__ sup,
                                                    const int* __restrict__ offs,
                                                    const unsigned* __restrict__ sedge,
                                                    const float* __restrict__ b1,
                                                    bf16* __restrict__ h1cat, int d0, int CHk) {
    const int i = blockIdx.x;
    const int g = i % CHk;
    const int nb = i / CHk;
    const int tid = threadIdx.x;
    const int lane = tid & 63;
    const int n = nb * 8 + ((tid >> 6) << 1) + (lane >> 5);
    const int hl = lane & 31;
    const int d = d0 + g;
    const int s = offs[d * (NN + 1) + n];
    const int e = offs[d * (NN + 1) + n + 1];
    const char* supd = (const char*)sup + (size_t)g * NN * NH * 2;
    const unsigned* sed = sedge + (size_t)d * NE;
    const unsigned hoff = (unsigned)hl * 4;
    float alo0 = 0.f, ahi0 = 0.f, alo1 = 0.f, ahi1 = 0.f;
    int j = s;
    for (; j + 4 <= e; j += 4) {
        unsigned e0 = sed[j], e1 = sed[j + 1], e2 = sed[j + 2], e3 = sed[j + 3];
        unsigned w0 = *(const unsigned*)(supd + (((e0 & 0xFFFFu) << 7) | hoff));
        unsigned w1 = *(const unsigned*)(supd + (((e1 & 0xFFFFu) << 7) | hoff));
        unsigned w2 = *(const unsigned*)(supd + (((e2 & 0xFFFFu) << 7) | hoff));
        unsigned w3 = *(const unsigned*)(supd + (((e3 & 0xFFFFu) << 7) | hoff));
        float v0 = bhi(e0), v1 = bhi(e1), v2 = bhi(e2), v3 = bhi(e3);
        alo0 = fmaf(v0, blo(w0), alo0); ahi0 = fmaf(v0, bhi(w0), ahi0);
        alo1 = fmaf(v1, blo(w1), alo1); ahi1 = fmaf(v1, bhi(w1), ahi1);
        alo0 = fmaf(v2, blo(w2), alo0); ahi0 = fmaf(v2, bhi(w2), ahi0);
        alo1 = fmaf(v3, blo(w3), alo1); ahi1 = fmaf(v3, bhi(w3), ahi1);
    }
    for (; j < e; ++j) {
        unsigned e0 = sed[j];
        unsigned w0 = *(const unsigned*)(supd + (((e0 & 0xFFFFu) << 7) | hoff));
        float v0 = bhi(e0);
        alo0 = fmaf(v0, blo(w0), alo0); ahi0 = fmaf(v0, bhi(w0), ahi0);
    }
    float alo = fmaxf((alo0 + alo1) + b1[d * NH + 2 * hl], 0.f);
    float ahi = fmaxf((ahi0 + ahi1) + b1[d * NH + 2 * hl + 1], 0.f);
    unsigned packed = bf16bits(alo) | (bf16bits(ahi) << 16);
    *(unsigned*)((char*)h1cat + ((size_t)n * K2 + d * NH) * 2 + hoff) = packed;
}

// ---------------- SPMM2 stage 1: branch d pinned to XCD d%8 (d=24 spread), relu'd bf16x2 ----------------
__global__ __launch_bounds__(256) void spmm2b_kernel(const bf16* __restrict__ sup2,
                                                     const int* __restrict__ offs,
                                                     const unsigned* __restrict__ sedge,
                                                     const float* __restrict__ b2,
                                                     unsigned* __restrict__ h2u) {
    const int i = blockIdx.x;
    const int r = i & 7;
    const int q = i >> 3;           // [0, 7813)
    int d, nb;
    if (q < 7500) { d = r + 8 * (q / 2500); nb = q % 2500; }
    else { d = 24; nb = (q - 7500) * 8 + r; if (nb >= 2500) return; }
    const int tid = threadIdx.x;
    const int lane = tid & 63;
    const int n = nb * 8 + ((tid >> 6) << 1) + (lane >> 5);
    const int cl = min(lane & 31, 24);      // class pair 2cl,2cl+1; lanes 25-31 dup
    const unsigned coff = (unsigned)cl * 4;
    const int s = offs[d * (NN + 1) + n];
    const int e = offs[d * (NN + 1) + n + 1];
    const char* supd = (const char*)sup2 + (size_t)d * NN * NC * 2;
    const unsigned* sed = sedge + (size_t)d * NE;
    float alo0 = b2[d * NC + 2 * cl], ahi0 = b2[d * NC + 2 * cl + 1];
    float alo1 = 0.f, ahi1 = 0.f;
    int j = s;
    for (; j + 4 <= e; j += 4) {
        unsigned e0 = sed[j], e1 = sed[j + 1], e2 = sed[j + 2], e3 = sed[j + 3];
        unsigned w0 = *(const unsigned*)(supd + ((e0 & 0xFFFFu) * 100u + coff));
        unsigned w1 = *(const unsigned*)(supd + ((e1 & 0xFFFFu) * 100u + coff));
        unsigned w2 = *(const unsigned*)(supd + ((e2 & 0xFFFFu) * 100u + coff));
        unsigned w3 = *(const unsigned*)(supd + ((e3 & 0xFFFFu) * 100u + coff));
        float v0 = bhi(e0), v1 = bhi(e1), v2 = bhi(e2), v3 = bhi(e3);
        alo0 = fmaf(v0, blo(w0), alo0); ahi0 = fmaf(v0, bhi(w0), ahi0);
        alo1 = fmaf(v1, blo(w1), alo1); ahi1 = fmaf(v1, bhi(w1), ahi1);
        alo0 = fmaf(v2, blo(w2), alo0); ahi0 = fmaf(v2, bhi(w2), ahi0);
        alo1 = fmaf(v3, blo(w3), alo1); ahi1 = fmaf(v3, bhi(w3), ahi1);
    }
    for (; j < e; ++j) {
        unsigned e0 = sed[j];
        unsigned w0 = *(const unsigned*)(supd + ((e0 & 0xFFFFu) * 100u + coff));
        float v0 = bhi(e0);
        alo0 = fmaf(v0, blo(w0), alo0); ahi0 = fmaf(v0, bhi(w0), ahi0);
    }
    float alo = fmaxf(alo0 + alo1, 0.f);
    float ahi = fmaxf(ahi0 + ahi1, 0.f);
    if ((lane & 31) < 25)
        h2u[((size_t)d * NN + n) * 25 + cl] = bf16bits(alo) | (bf16bits(ahi) << 16);
}

// ---------------- SPMM2 stage 2: streaming max over branches ----------------
__global__ __launch_bounds__(256) void maxk_kernel(const unsigned* __restrict__ h2u,
                                                   float* __restrict__ out) {
    int i = blockIdx.x * blockDim.x + threadIdx.x;   // [0, NN*25)
    if (i >= NN * 25) return;
    int n = i / 25, cl = i - n * 25;
    float mlo = 0.f, mhi = 0.f;
    #pragma unroll
    for (int d = 0; d < DIM; ++d) {
        unsigned w = h2u[(size_t)d * NN * 25 + i];
        mlo = fmaxf(mlo, blo(w));
        mhi = fmaxf(mhi, bhi(w));
    }
    *(float2*)&out[(size_t)n * NC + 2 * cl] = make_float2(mlo, mhi);
}

extern "C" void kernel_launch(void* const* d_in, const int* in_sizes, int n_in,
                              void* d_out, int out_size, void* d_ws, size_t ws_size,
                              hipStream_t stream) {
    const float* x    = (const float*)d_in[0];
    const int*   rows = (const int*)d_in[1];
    const int*   cols = (const int*)d_in[2];
    const float* vals = (const float*)d_in[3];
    const float* W1   = (const float*)d_in[4];
    const float* b1   = (const float*)d_in[5];
    const float* W2   = (const float*)d_in[6];
    const float* b2   = (const float*)d_in[7];
    float* out = (float*)d_out;

    char* ws = (char*)d_ws;
    size_t off = 0;
    auto alloc = [&](size_t bytes) {
        void* p = ws + off;
        off += (bytes + 255) & ~(size_t)255;
        return p;
    };
    bf16* supbuf = (bf16*)alloc(sizeof(bf16) * (size_t)DIM * NN * NC);   // 50 MB
    bf16* h1cat  = (bf16*)alloc(sizeof(bf16) * (size_t)NN * K2);         // 64 MB (aliases inter & h2)
    bf16* b1t    = (bf16*)alloc(sizeof(bf16) * (size_t)B1T_ROWS * KP1);  // 1.07 MB
    bf16* b2t    = (bf16*)alloc(sizeof(bf16) * (size_t)B2T_ROWS * K2);   // 4.1 MB
    int*  offs   = (int*)alloc(sizeof(int) * (size_t)DIM * (NN + 1));    // 2 MB
    int*  gcur   = (int*)alloc(sizeof(int) * (size_t)DIM * NBK);
    int*  offs_b = (int*)alloc(sizeof(int) * (size_t)DIM * NBK);
    int*  bcnt   = (int*)alloc(sizeof(int) * (size_t)DIM * NBK);
    unsigned* sedge = (unsigned*)alloc(sizeof(unsigned) * (size_t)DIM * NE); // 32 MB

    bf16* sup1 = supbuf;                                   // [<=8][NN][64] = 20.5 MB
    bf16* xbf  = supbuf + (size_t)12 * 1024 * 1024;        // +24 MB (12.8 MB)
    bf16* sup2 = supbuf;                                   // [25][NN][50]
    unsigned* interE = (unsigned*)h1cat;
    unsigned char* interR = (unsigned char*)h1cat + (size_t)DIM * NBK * FCAP * 4;
    unsigned* h2u = (unsigned*)h1cat;                      // 50 MB, h1cat dead after gemm2

    if (off > ws_size) return;  // diagnostic guard (~153 MB, known-safe)

    // CSR build
    zero_kernel<<<(DIM * NBK + 255) / 256, 256, 0, stream>>>(gcur, DIM * NBK);
    bucket_scatter_kernel<<<dim3(BPB, DIM), 256, 0, stream>>>(rows, cols, vals, gcur, interE, interR);
    bucket_scan_kernel<<<DIM, 64, 0, stream>>>(gcur, offs_b, bcnt, offs);
    csr_finalize_kernel<<<dim3(NBK, DIM), 256, 0, stream>>>(interE, interR, offs_b, bcnt, offs, sedge);

    // Packing
    pack_x_kernel<<<(NN * KP1 + 255) / 256, 256, 0, stream>>>(x, xbf);
    pack_b1_kernel<<<(B1T_ROWS * KP1 + 255) / 256, 256, 0, stream>>>(W1, b1t);
    pack_b2_kernel<<<(B2T_ROWS * K2 + 255) / 256, 256, 0, stream>>>(W2, b2t);

    const int mtiles128 = (NN + 127) / 128;  // 157
    const int mtiles256 = (NN + 255) / 256;  // 79

    // Layer 1: chunks {8,8,8,1} branches; 512-col chunks use the 256^2 8-wave kernel
    const int cstart[4] = {0, 8, 16, 24};
    const int csize[4]  = {8, 8, 8, 1};
    const int crow[4]   = {0, 512, 1024, 1536};
    for (int c = 0; c < 3; ++c) {
        gemm256_bf16_kernel<<<dim3(mtiles256, 2), 512, 0, stream>>>(
            xbf, KP1, b1t + (size_t)crow[c] * KP1, KP1, sup1, KP1 / 64, 1, 512);
        spmm1_kernel<<<csize[c] * (NN / 8), 256, 0, stream>>>(
            sup1, offs, sedge, b1, h1cat, cstart[c], csize[c]);
    }
    // last chunk: 1 branch, 64 cols -> legacy 128^2 kernel
    gemm_bf16_kernel<<<dim3(mtiles128, 1), 256, 0, stream>>>(
        xbf, KP1, b1t + (size_t)crow[3] * KP1, KP1, sup1, KP1 / 32, 1, 64);
    spmm1_kernel<<<csize[3] * (NN / 8), 256, 0, stream>>>(
        sup1, offs, sedge, b1, h1cat, cstart[3], csize[3]);

    // Layer 2: GEMM [20000x1600]@[1600x1280] -> sup2; branch-pinned spmm2 -> h2; max -> out
    gemm256_bf16_kernel<<<dim3(mtiles256, B2T_ROWS / 256), 512, 0, stream>>>(
        h1cat, K2, b2t, K2, sup2, K2 / 64, 2, DIM * NC);
    spmm2b_kernel<<<8 * 7813, 256, 0, stream>>>(sup2, offs, sedge, b2, h2u);
    maxk_kernel<<<(NN * 25 + 255) / 256, 256, 0, stream>>>(h2u, out);
}